// Round 6
// baseline (743.731 us; speedup 1.0000x reference)
//
#include <hip/hip_runtime.h>
#include <hip/hip_bf16.h>
#include <stdint.h>

// Problem constants (match reference)
#define B_   4
#define S_   2048
#define H_   2048
#define NH_  16
#define NKV_ 4
#define HD_  128
#define F_   3072   // H + 2*NKV*HD

typedef __bf16 bf16x8 __attribute__((ext_vector_type(8)));
typedef float  f32x4  __attribute__((ext_vector_type(4)));
typedef unsigned short u16;

// global_load_lds: LDS dest is WAVE-UNIFORM base + lane*16 (m104); source is per-lane.
#define GLOAD_LDS16(gp, lp)                                                             \
  __builtin_amdgcn_global_load_lds((const __attribute__((address_space(1))) void*)(gp), \
                                   (__attribute__((address_space(3))) void*)(lp), 16, 0, 0)

__device__ __forceinline__ u16 f2bf(float f) {
  union { float f; uint32_t u; } v; v.f = f;
  uint32_t r = (v.u + 0x7FFFu + ((v.u >> 16) & 1u)) >> 16;  // RNE
  return (u16)r;
}
__device__ __forceinline__ float bf2f(u16 u) {
  union { uint32_t u; float f; } v; v.u = ((uint32_t)u) << 16;
  return v.f;
}

// ---------------- elementwise f32 -> bf16 ----------------
__global__ void k_cvt_bf16(const float* __restrict__ in, u16* __restrict__ out, int n4) {
  int i = blockIdx.x * 256 + threadIdx.x;
  if (i >= n4) return;
  float4 v = ((const float4*)in)[i];
  union { u16 s[4]; uint2 u; } o;
  o.s[0] = f2bf(v.x); o.s[1] = f2bf(v.y); o.s[2] = f2bf(v.z); o.s[3] = f2bf(v.w);
  ((uint2*)out)[i] = o.u;
}

// ---------------- tiled transpose + cvt: out[c][r] = bf16(in[r][c]) ----------------
__global__ void k_transpose_cvt(const float* __restrict__ in, u16* __restrict__ out, int R, int C) {
  __shared__ u16 tile[64][68];
  int c0 = blockIdx.x * 64, r0 = blockIdx.y * 64;
  int t = threadIdx.x;
#pragma unroll
  for (int j = 0; j < 16; ++j) {
    int e = j * 256 + t;
    int r = e >> 6, c = e & 63;
    tile[r][c] = f2bf(in[(size_t)(r0 + r) * C + (c0 + c)]);
  }
  __syncthreads();
#pragma unroll
  for (int j = 0; j < 16; ++j) {
    int e = j * 256 + t;
    int c = e >> 6, r = e & 63;
    out[(size_t)(c0 + c) * R + (r0 + r)] = tile[r][c];
  }
}

// ---------------- bf16 GEMM: C[M][N] = A[M][K] * BT[N][K]^T ----------------
// r5 (kept): T3-minimum double-buffered pipeline + T2 both-sides XOR swizzle.
template <bool OUTF32>
__global__ __launch_bounds__(256) void k_gemm_bt(const u16* __restrict__ A, const u16* __restrict__ BT,
                                                 void* __restrict__ Cv, int M, int N, int K) {
  __shared__ u16 lA[2][128 * 64];
  __shared__ u16 lB[2][128 * 64];
  int t = threadIdx.x, w = t >> 6, l = t & 63, c = l & 15, g = l >> 4;
  int bn = blockIdx.x * 128, bm = blockIdx.y * 128;
  int wm = (w >> 1) * 64, wn = (w & 1) * 64;

  f32x4 acc[4][4];
#pragma unroll
  for (int mi = 0; mi < 4; ++mi)
#pragma unroll
    for (int ni = 0; ni < 4; ++ni) acc[mi][ni] = (f32x4){0.f, 0.f, 0.f, 0.f};

  int nk = K >> 6;
  int srow = l >> 3;                       // row within 1KB chunk (8 rows x 64 u16)
  int scol = ((l & 7) ^ srow) * 8;         // inverse-swizzled source column chunk

#define GEMM_STAGE(k0, buf)                                                     \
  _Pragma("unroll")                                                             \
  for (int i = 0; i < 4; ++i) {                                                 \
    int ch = i * 4 + w; int row = ch * 8 + srow;                                \
    GLOAD_LDS16(&A [(size_t)(bm + row) * K + (k0) + scol], &lA[buf][ch * 512]); \
    GLOAD_LDS16(&BT[(size_t)(bn + row) * K + (k0) + scol], &lB[buf][ch * 512]); \
  }

  GEMM_STAGE(0, 0)
  asm volatile("s_waitcnt vmcnt(0)" ::: "memory");
  __syncthreads();
  int cur = 0;
  for (int kt = 0; kt < nk; ++kt) {
    if (kt + 1 < nk) { GEMM_STAGE((kt + 1) << 6, cur ^ 1) }
    const u16* cA = lA[cur];
    const u16* cB = lB[cur];
#pragma unroll
    for (int s = 0; s < 2; ++s) {
      bf16x8 af[4], bfr[4];
#pragma unroll
      for (int mi = 0; mi < 4; ++mi) {
        int row = wm + mi * 16 + c;        // row&7 = c&7
        af[mi] = *(const bf16x8*)&cA[row * 64 + (((s * 4 + g) ^ (c & 7)) * 8)];
      }
#pragma unroll
      for (int ni = 0; ni < 4; ++ni) {
        int row = wn + ni * 16 + c;
        bfr[ni] = *(const bf16x8*)&cB[row * 64 + (((s * 4 + g) ^ (c & 7)) * 8)];
      }
#pragma unroll
      for (int mi = 0; mi < 4; ++mi)
#pragma unroll
        for (int ni = 0; ni < 4; ++ni)
          acc[mi][ni] = __builtin_amdgcn_mfma_f32_16x16x32_bf16(af[mi], bfr[ni], acc[mi][ni], 0, 0, 0);
    }
    if (kt + 1 < nk) {
      asm volatile("s_waitcnt vmcnt(0)" ::: "memory");
      __syncthreads();
      cur ^= 1;
    }
  }
  // epilogue: D row = 4*g + r, col = c  (m89/m91-verified layout)
#pragma unroll
  for (int mi = 0; mi < 4; ++mi)
#pragma unroll
    for (int ni = 0; ni < 4; ++ni)
#pragma unroll
      for (int r = 0; r < 4; ++r) {
        size_t row = (size_t)bm + wm + mi * 16 + 4 * g + r;
        size_t col = (size_t)bn + wn + ni * 16 + c;
        if constexpr (OUTF32) ((float*)Cv)[row * N + col] = acc[mi][ni][r];
        else                  ((u16*)Cv)  [row * N + col] = f2bf(acc[mi][ni][r]);
      }
#undef GEMM_STAGE
}

// ---------------- RoPE + scatter Q/K from qkv ----------------
__global__ void k_rope_qk(const u16* __restrict__ qkv, const float* __restrict__ ct,
                          const float* __restrict__ st, u16* __restrict__ Q, u16* __restrict__ Kd) {
  size_t idx = (size_t)blockIdx.x * 256 + threadIdx.x;
  const size_t NQ = (size_t)B_ * NH_ * S_ * HD_;  // 2^24
  int d, s, row, col; size_t oidx; u16* dst;
  if (idx < NQ) {
    d = (int)(idx & 127); s = (int)((idx >> 7) & (S_ - 1));
    int h = (int)((idx >> 18) & 15); int b = (int)(idx >> 22);
    row = b * S_ + s;
    col = (h >> 2) * 768 + (h & 3) * 128 + d;
    dst = Q; oidx = idx;
  } else {
    size_t i2 = idx - NQ;
    d = (int)(i2 & 127); s = (int)((i2 >> 7) & (S_ - 1));
    int kvh = (int)((i2 >> 18) & 3); int b = (int)(i2 >> 20);
    row = b * S_ + s;
    col = kvh * 768 + 512 + d;
    dst = Kd; oidx = i2;
  }
  float x  = bf2f(qkv[(size_t)row * F_ + col]);
  float xr = (d < 64) ? -bf2f(qkv[(size_t)row * F_ + col + 64])
                      :  bf2f(qkv[(size_t)row * F_ + col - 64]);
  float o = x * ct[s * HD_ + d] + xr * st[s * HD_ + d];
  dst[oidx] = f2bf(o);
}

// ---------------- V transpose: Vt[b][kvh][d][s] = qkv V part ----------------
__global__ void k_transpose_v(const u16* __restrict__ qkv, u16* __restrict__ Vt) {
  __shared__ u16 tile[64][136];
  int s0 = blockIdx.x * 64;
  int b = blockIdx.y >> 2, kvh = blockIdx.y & 3;
  int t = threadIdx.x;
  const u16* src = qkv + (size_t)(b * S_ + s0) * F_ + kvh * 768 + 640;
#pragma unroll
  for (int j = 0; j < 4; ++j) {
    int e = j * 256 + t;
    int sl = e >> 4, ch = e & 15;
    *(uint4*)&tile[sl][ch * 8] = *(const uint4*)&src[(size_t)sl * F_ + ch * 8];
  }
  __syncthreads();
  u16* dstb = Vt + (size_t)(b * NKV_ + kvh) * HD_ * S_;
#pragma unroll
  for (int j = 0; j < 4; ++j) {
    int e = j * 256 + t;
    int d = e & 127, sc = e >> 7;
    u16 tmp[8];
#pragma unroll
    for (int i = 0; i < 8; ++i) tmp[i] = tile[sc * 8 + i][d];
    *(uint4*)&dstb[(size_t)d * S_ + s0 + sc * 8] = *(const uint4*)tmp;
  }
}

// ---------------- flash attention (causal, GQA) ----------------
// r6: QBLK=128, 8 waves/block (512 thr), SINGLE-buffered K/V (r5 lesson: dbuf's LDS
// cost kills TLP). One 32KB K/V stage now feeds 8 waves (2x arithmetic intensity per
// staged byte); K/V re-read traffic halves; 48KB LDS -> 3 blocks/CU = 24 waves/CU.
__global__ __launch_bounds__(512, 6) void k_flash(const u16* __restrict__ Q, const u16* __restrict__ K,
                                                  const u16* __restrict__ Vt, u16* __restrict__ O) {
  __shared__ u16 lK[64 * 128];      // [kv][chunk^(kv&15)] swizzled, 16B chunks
  __shared__ u16 lV[128 * 64];      // [d][chunk^(d&7)] swizzled, 16B chunks
  __shared__ u16 lP[8][16 * 64];    // per-wave [q][kv], chunk ^ (q&7) swizzle (reg-written)
  int t = threadIdx.x, w = t >> 6, l = t & 63, c = l & 15, g = l >> 4;
  int qb = (int)(gridDim.x - 1 - blockIdx.x);   // heavy blocks first
  int bh = blockIdx.y;
  int b = bh >> 4, h = bh & 15, kvh = h >> 2;
  int qw = qb * 128 + w * 16;
  const u16* Qb = Q  + (size_t)(b * NH_  + h)   * S_ * HD_;
  const u16* Kb = K  + (size_t)(b * NKV_ + kvh) * S_ * HD_;
  const u16* Vb = Vt + (size_t)(b * NKV_ + kvh) * HD_ * S_;

  bf16x8 qf[4];
#pragma unroll
  for (int sl = 0; sl < 4; ++sl)
    qf[sl] = *(const bf16x8*)&Qb[(size_t)(qw + c) * HD_ + sl * 32 + g * 8];

  f32x4 oacc[8];
#pragma unroll
  for (int nd = 0; nd < 8; ++nd) oacc[nd] = (f32x4){0.f, 0.f, 0.f, 0.f};
  float m_run = -1e30f, l_run = 0.f;

  int ntiles = 2 * qb + 2;
  int krl = l >> 4;                 // local K row in chunk (0..3)
  int vrl = l >> 3;                 // local V row in chunk (0..7)

  for (int kt = 0; kt < ntiles; ++kt) {
    int kv0 = kt * 64;
    __syncthreads();
#pragma unroll
    for (int i = 0; i < 2; ++i) {   // 16 chunks over 8 waves
      int ch = i * 8 + w;
      int rrK = ch * 4 + krl;
      int jK  = (l & 15) ^ (rrK & 15);
      GLOAD_LDS16(&Kb[(size_t)(kv0 + rrK) * HD_ + jK * 8], &lK[ch * 512]);
      int rdV = ch * 8 + vrl;
      int jV  = (l & 7) ^ (rdV & 7);
      GLOAD_LDS16(&Vb[(size_t)rdV * S_ + kv0 + jV * 8], &lV[ch * 512]);
    }
    asm volatile("s_waitcnt vmcnt(0)" ::: "memory");
    __syncthreads();
    if (kv0 <= qw + 15) {           // wave-uniform causal skip
      f32x4 sc[4];
#pragma unroll
      for (int f = 0; f < 4; ++f) sc[f] = (f32x4){0.f, 0.f, 0.f, 0.f};
#pragma unroll
      for (int sl = 0; sl < 4; ++sl)
#pragma unroll
        for (int f = 0; f < 4; ++f) {
          // row = f*16+c, row&15 = c -> swizzled chunk = (sl*4+g) ^ c
          bf16x8 kf = *(const bf16x8*)&lK[(f * 16 + c) * 128 + (((sl * 4 + g) ^ c) * 8)];
          sc[f] = __builtin_amdgcn_mfma_f32_16x16x32_bf16(kf, qf[sl], sc[f], 0, 0, 0);
        }
      const float SCL = 0.088388347648318447f * 1.4426950408889634f;  // 1/sqrt(128)*log2(e)
      bool partial = (kv0 + 63 > qw);
      float pvv[4][4];
      float pm = -1e30f;
#pragma unroll
      for (int f = 0; f < 4; ++f)
#pragma unroll
        for (int r = 0; r < 4; ++r) {
          float v = sc[f][r] * SCL;  // S^T: kv = kv0+f*16+4g+r, q = qw+c
          if (partial && (kv0 + f * 16 + 4 * g + r > qw + c)) v = -1e30f;
          pvv[f][r] = v;
          pm = fmaxf(pm, v);
        }
      pm = fmaxf(pm, __shfl_xor(pm, 16));
      pm = fmaxf(pm, __shfl_xor(pm, 32));
      float m_new = fmaxf(m_run, pm);
      float alpha = exp2f(m_run - m_new);
      float ps = 0.f;
#pragma unroll
      for (int f = 0; f < 4; ++f)
#pragma unroll
        for (int r = 0; r < 4; ++r) {
          float p = exp2f(pvv[f][r] - m_new);
          pvv[f][r] = p;
          ps += p;
        }
      ps += __shfl_xor(ps, 16);
      ps += __shfl_xor(ps, 32);
      l_run = l_run * alpha + ps;
      m_run = m_new;
#pragma unroll
      for (int r = 0; r < 4; ++r) {
        float ar = __shfl(alpha, 4 * g + r);
#pragma unroll
        for (int nd = 0; nd < 8; ++nd) oacc[nd][r] *= ar;
      }
      // P -> per-wave LDS tile [q][kv] (bf16, swizzled; register-written so swizzle OK)
      char* Pw = (char*)&lP[w][0];
#pragma unroll
      for (int f = 0; f < 4; ++f) {
        int base = f * 32 + g * 8;
        int chunk = base >> 4, within = base & 15;
        uint32_t p01 = (uint32_t)f2bf(pvv[f][0]) | ((uint32_t)f2bf(pvv[f][1]) << 16);
        uint32_t p23 = (uint32_t)f2bf(pvv[f][2]) | ((uint32_t)f2bf(pvv[f][3]) << 16);
        int rowb = c * 128 + ((chunk ^ (c & 7)) << 4) + within;
        *(uint32_t*)(Pw + rowb)     = p01;
        *(uint32_t*)(Pw + rowb + 4) = p23;
      }
      // PV: O[q][d] += P[q][kv] * V[kv][d]
#pragma unroll
      for (int ks = 0; ks < 2; ++ks) {
        bf16x8 pf = *(const bf16x8*)(Pw + c * 128 + (((ks * 4 + g) ^ (c & 7)) << 4));
#pragma unroll
        for (int nd = 0; nd < 8; ++nd) {
          int rowv = nd * 16 + c;   // rowv&7 = c&7
          bf16x8 vf = *(const bf16x8*)&lV[rowv * 64 + (((ks * 4 + g) ^ (c & 7)) * 8)];
          oacc[nd] = __builtin_amdgcn_mfma_f32_16x16x32_bf16(pf, vf, oacc[nd], 0, 0, 0);
        }
      }
    }
  }
  float lr[4];
#pragma unroll
  for (int r = 0; r < 4; ++r) {
    float lv = __shfl(l_run, 4 * g + r);
    lr[r] = 1.f / lv;
  }
#pragma unroll
  for (int nd = 0; nd < 8; ++nd)
#pragma unroll
    for (int r = 0; r < 4; ++r) {
      size_t row = (size_t)b * S_ + (qw + 4 * g + r);
      O[row * (NH_ * HD_) + h * HD_ + nd * 16 + c] = f2bf(oacc[nd][r] * lr[r]);
    }
}

// ---------------- launch ----------------
extern "C" void kernel_launch(void* const* d_in, const int* in_sizes, int n_in,
                              void* d_out, int out_size, void* d_ws, size_t ws_size,
                              hipStream_t stream) {
  const float* hid   = (const float*)d_in[0];
  // d_in[1] attention_mask: deterministic causal mask -> implemented directly
  const float* rcos  = (const float*)d_in[2];
  const float* rsin  = (const float*)d_in[3];
  const float* wattn = (const float*)d_in[4];
  const float* wproj = (const float*)d_in[5];

  // ws layout (u16 units). Required: ~148 MiB.
  u16* ws   = (u16*)d_ws;
  u16* hidB = ws;                 // 8192*2048
  u16* wAT  = ws + 16777216;      // 3072*2048 (w_attn^T)
  u16* wPT  = ws + 23068672;      // 2048*2048 (w_proj^T)
  u16* qkv  = ws + 27262976;      // 8192*3072
  u16* Qs   = ws + 52428800;      // [B][NH][S][HD]
  u16* Ks   = ws + 69206016;      // [B][NKV][S][HD]
  u16* Vts  = ws + 73400320;      // [B][NKV][HD][S]
  u16* Os   = qkv;                // alias: qkv dead after rope/transpose_v

  k_cvt_bf16<<<16384, 256, 0, stream>>>(hid, hidB, 16777216 / 4);
  k_transpose_cvt<<<dim3(48, 32), 256, 0, stream>>>(wattn, wAT, 2048, 3072);
  k_transpose_cvt<<<dim3(32, 32), 256, 0, stream>>>(wproj, wPT, 2048, 2048);
  k_gemm_bt<false><<<dim3(24, 64), 256, 0, stream>>>(hidB, wAT, qkv, 8192, 3072, 2048);
  k_rope_qk<<<81920, 256, 0, stream>>>(qkv, rcos, rsin, Qs, Ks);
  k_transpose_v<<<dim3(32, 16), 256, 0, stream>>>(qkv, Vts);
  k_flash<<<dim3(16, 64), 512, 0, stream>>>(Qs, Ks, Vts, Os);
  k_gemm_bt<true><<<dim3(16, 64), 256, 0, stream>>>(Os, wPT, d_out, 8192, 2048, 2048);
}

// Round 7
// 611.477 us; speedup vs baseline: 1.2163x; 1.2163x over previous
//
#include <hip/hip_runtime.h>
#include <hip/hip_bf16.h>
#include <stdint.h>

// Problem constants (match reference)
#define B_   4
#define S_   2048
#define H_   2048
#define NH_  16
#define NKV_ 4
#define HD_  128
#define F_   3072   // H + 2*NKV*HD

typedef __bf16 bf16x8 __attribute__((ext_vector_type(8)));
typedef float  f32x4  __attribute__((ext_vector_type(4)));
typedef unsigned short u16;

// global_load_lds: LDS dest is WAVE-UNIFORM base + lane*16 (m104); source is per-lane.
#define GLOAD_LDS16(gp, lp)                                                             \
  __builtin_amdgcn_global_load_lds((const __attribute__((address_space(1))) void*)(gp), \
                                   (__attribute__((address_space(3))) void*)(lp), 16, 0, 0)

__device__ __forceinline__ u16 f2bf(float f) {
  union { float f; uint32_t u; } v; v.f = f;
  uint32_t r = (v.u + 0x7FFFu + ((v.u >> 16) & 1u)) >> 16;  // RNE
  return (u16)r;
}
__device__ __forceinline__ float bf2f(u16 u) {
  union { uint32_t u; float f; } v; v.u = ((uint32_t)u) << 16;
  return v.f;
}

// ---------------- elementwise f32 -> bf16 ----------------
__global__ void k_cvt_bf16(const float* __restrict__ in, u16* __restrict__ out, int n4) {
  int i = blockIdx.x * 256 + threadIdx.x;
  if (i >= n4) return;
  float4 v = ((const float4*)in)[i];
  union { u16 s[4]; uint2 u; } o;
  o.s[0] = f2bf(v.x); o.s[1] = f2bf(v.y); o.s[2] = f2bf(v.z); o.s[3] = f2bf(v.w);
  ((uint2*)out)[i] = o.u;
}

// ---------------- tiled transpose + cvt: out[c][r] = bf16(in[r][c]) ----------------
__global__ void k_transpose_cvt(const float* __restrict__ in, u16* __restrict__ out, int R, int C) {
  __shared__ u16 tile[64][68];
  int c0 = blockIdx.x * 64, r0 = blockIdx.y * 64;
  int t = threadIdx.x;
#pragma unroll
  for (int j = 0; j < 16; ++j) {
    int e = j * 256 + t;
    int r = e >> 6, c = e & 63;
    tile[r][c] = f2bf(in[(size_t)(r0 + r) * C + (c0 + c)]);
  }
  __syncthreads();
#pragma unroll
  for (int j = 0; j < 16; ++j) {
    int e = j * 256 + t;
    int c = e >> 6, r = e & 63;
    out[(size_t)(c0 + c) * R + (r0 + r)] = tile[r][c];
  }
}

// ---------------- bf16 GEMM: C[M][N] = A[M][K] * BT[N][K]^T ----------------
// r5 (kept): T3-minimum double-buffered pipeline + T2 both-sides XOR swizzle.
template <bool OUTF32>
__global__ __launch_bounds__(256) void k_gemm_bt(const u16* __restrict__ A, const u16* __restrict__ BT,
                                                 void* __restrict__ Cv, int M, int N, int K) {
  __shared__ u16 lA[2][128 * 64];
  __shared__ u16 lB[2][128 * 64];
  int t = threadIdx.x, w = t >> 6, l = t & 63, c = l & 15, g = l >> 4;
  int bn = blockIdx.x * 128, bm = blockIdx.y * 128;
  int wm = (w >> 1) * 64, wn = (w & 1) * 64;

  f32x4 acc[4][4];
#pragma unroll
  for (int mi = 0; mi < 4; ++mi)
#pragma unroll
    for (int ni = 0; ni < 4; ++ni) acc[mi][ni] = (f32x4){0.f, 0.f, 0.f, 0.f};

  int nk = K >> 6;
  int srow = l >> 3;                       // row within 1KB chunk (8 rows x 64 u16)
  int scol = ((l & 7) ^ srow) * 8;         // inverse-swizzled source column chunk

#define GEMM_STAGE(k0, buf)                                                     \
  _Pragma("unroll")                                                             \
  for (int i = 0; i < 4; ++i) {                                                 \
    int ch = i * 4 + w; int row = ch * 8 + srow;                                \
    GLOAD_LDS16(&A [(size_t)(bm + row) * K + (k0) + scol], &lA[buf][ch * 512]); \
    GLOAD_LDS16(&BT[(size_t)(bn + row) * K + (k0) + scol], &lB[buf][ch * 512]); \
  }

  GEMM_STAGE(0, 0)
  asm volatile("s_waitcnt vmcnt(0)" ::: "memory");
  __syncthreads();
  int cur = 0;
  for (int kt = 0; kt < nk; ++kt) {
    if (kt + 1 < nk) { GEMM_STAGE((kt + 1) << 6, cur ^ 1) }
    const u16* cA = lA[cur];
    const u16* cB = lB[cur];
#pragma unroll
    for (int s = 0; s < 2; ++s) {
      bf16x8 af[4], bfr[4];
#pragma unroll
      for (int mi = 0; mi < 4; ++mi) {
        int row = wm + mi * 16 + c;        // row&7 = c&7
        af[mi] = *(const bf16x8*)&cA[row * 64 + (((s * 4 + g) ^ (c & 7)) * 8)];
      }
#pragma unroll
      for (int ni = 0; ni < 4; ++ni) {
        int row = wn + ni * 16 + c;
        bfr[ni] = *(const bf16x8*)&cB[row * 64 + (((s * 4 + g) ^ (c & 7)) * 8)];
      }
#pragma unroll
      for (int mi = 0; mi < 4; ++mi)
#pragma unroll
        for (int ni = 0; ni < 4; ++ni)
          acc[mi][ni] = __builtin_amdgcn_mfma_f32_16x16x32_bf16(af[mi], bfr[ni], acc[mi][ni], 0, 0, 0);
    }
    if (kt + 1 < nk) {
      asm volatile("s_waitcnt vmcnt(0)" ::: "memory");
      __syncthreads();
      cur ^= 1;
    }
  }
  // epilogue: D row = 4*g + r, col = c  (m89/m91-verified layout)
#pragma unroll
  for (int mi = 0; mi < 4; ++mi)
#pragma unroll
    for (int ni = 0; ni < 4; ++ni)
#pragma unroll
      for (int r = 0; r < 4; ++r) {
        size_t row = (size_t)bm + wm + mi * 16 + 4 * g + r;
        size_t col = (size_t)bn + wn + ni * 16 + c;
        if constexpr (OUTF32) ((float*)Cv)[row * N + col] = acc[mi][ni][r];
        else                  ((u16*)Cv)  [row * N + col] = f2bf(acc[mi][ni][r]);
      }
#undef GEMM_STAGE
}

// ---------------- RoPE + scatter Q/K from qkv ----------------
__global__ void k_rope_qk(const u16* __restrict__ qkv, const float* __restrict__ ct,
                          const float* __restrict__ st, u16* __restrict__ Q, u16* __restrict__ Kd) {
  size_t idx = (size_t)blockIdx.x * 256 + threadIdx.x;
  const size_t NQ = (size_t)B_ * NH_ * S_ * HD_;  // 2^24
  int d, s, row, col; size_t oidx; u16* dst;
  if (idx < NQ) {
    d = (int)(idx & 127); s = (int)((idx >> 7) & (S_ - 1));
    int h = (int)((idx >> 18) & 15); int b = (int)(idx >> 22);
    row = b * S_ + s;
    col = (h >> 2) * 768 + (h & 3) * 128 + d;
    dst = Q; oidx = idx;
  } else {
    size_t i2 = idx - NQ;
    d = (int)(i2 & 127); s = (int)((i2 >> 7) & (S_ - 1));
    int kvh = (int)((i2 >> 18) & 3); int b = (int)(i2 >> 20);
    row = b * S_ + s;
    col = kvh * 768 + 512 + d;
    dst = Kd; oidx = i2;
  }
  float x  = bf2f(qkv[(size_t)row * F_ + col]);
  float xr = (d < 64) ? -bf2f(qkv[(size_t)row * F_ + col + 64])
                      :  bf2f(qkv[(size_t)row * F_ + col - 64]);
  float o = x * ct[s * HD_ + d] + xr * st[s * HD_ + d];
  dst[oidx] = f2bf(o);
}

// ---------------- V transpose: Vt[b][kvh][d][s] = qkv V part ----------------
__global__ void k_transpose_v(const u16* __restrict__ qkv, u16* __restrict__ Vt) {
  __shared__ u16 tile[64][136];
  int s0 = blockIdx.x * 64;
  int b = blockIdx.y >> 2, kvh = blockIdx.y & 3;
  int t = threadIdx.x;
  const u16* src = qkv + (size_t)(b * S_ + s0) * F_ + kvh * 768 + 640;
#pragma unroll
  for (int j = 0; j < 4; ++j) {
    int e = j * 256 + t;
    int sl = e >> 4, ch = e & 15;
    *(uint4*)&tile[sl][ch * 8] = *(const uint4*)&src[(size_t)sl * F_ + ch * 8];
  }
  __syncthreads();
  u16* dstb = Vt + (size_t)(b * NKV_ + kvh) * HD_ * S_;
#pragma unroll
  for (int j = 0; j < 4; ++j) {
    int e = j * 256 + t;
    int d = e & 127, sc = e >> 7;
    u16 tmp[8];
#pragma unroll
    for (int i = 0; i < 8; ++i) tmp[i] = tile[sc * 8 + i][d];
    *(uint4*)&dstb[(size_t)d * S_ + s0 + sc * 8] = *(const uint4*)tmp;
  }
}

// ---------------- flash attention (causal, GQA) ----------------
// r7: r6's QBLK=128 / 8-wave structure, but __launch_bounds__(512, 4) — r6's (512,6)
// capped unified VGPR at ~85, leaving ~40 arch regs -> massive scratch spill
// (FETCH 308MB, WRITE 120MB). (512,4) gives the r4-proven 128-reg budget:
// 2 blocks/CU x 8 waves = 16 waves/CU (same occupancy as r4, half the staging).
__global__ __launch_bounds__(512, 4) void k_flash(const u16* __restrict__ Q, const u16* __restrict__ K,
                                                  const u16* __restrict__ Vt, u16* __restrict__ O) {
  __shared__ u16 lK[64 * 128];      // [kv][chunk^(kv&15)] swizzled, 16B chunks
  __shared__ u16 lV[128 * 64];      // [d][chunk^(d&7)] swizzled, 16B chunks
  __shared__ u16 lP[8][16 * 64];    // per-wave [q][kv], chunk ^ (q&7) swizzle (reg-written)
  int t = threadIdx.x, w = t >> 6, l = t & 63, c = l & 15, g = l >> 4;
  int qb = (int)(gridDim.x - 1 - blockIdx.x);   // heavy blocks first
  int bh = blockIdx.y;
  int b = bh >> 4, h = bh & 15, kvh = h >> 2;
  int qw = qb * 128 + w * 16;
  const u16* Qb = Q  + (size_t)(b * NH_  + h)   * S_ * HD_;
  const u16* Kb = K  + (size_t)(b * NKV_ + kvh) * S_ * HD_;
  const u16* Vb = Vt + (size_t)(b * NKV_ + kvh) * HD_ * S_;

  bf16x8 qf[4];
#pragma unroll
  for (int sl = 0; sl < 4; ++sl)
    qf[sl] = *(const bf16x8*)&Qb[(size_t)(qw + c) * HD_ + sl * 32 + g * 8];

  f32x4 oacc[8];
#pragma unroll
  for (int nd = 0; nd < 8; ++nd) oacc[nd] = (f32x4){0.f, 0.f, 0.f, 0.f};
  float m_run = -1e30f, l_run = 0.f;

  int ntiles = 2 * qb + 2;
  int krl = l >> 4;                 // local K row in chunk (0..3)
  int vrl = l >> 3;                 // local V row in chunk (0..7)

  for (int kt = 0; kt < ntiles; ++kt) {
    int kv0 = kt * 64;
    __syncthreads();
#pragma unroll
    for (int i = 0; i < 2; ++i) {   // 16 chunks over 8 waves
      int ch = i * 8 + w;
      int rrK = ch * 4 + krl;
      int jK  = (l & 15) ^ (rrK & 15);
      GLOAD_LDS16(&Kb[(size_t)(kv0 + rrK) * HD_ + jK * 8], &lK[ch * 512]);
      int rdV = ch * 8 + vrl;
      int jV  = (l & 7) ^ (rdV & 7);
      GLOAD_LDS16(&Vb[(size_t)rdV * S_ + kv0 + jV * 8], &lV[ch * 512]);
    }
    asm volatile("s_waitcnt vmcnt(0)" ::: "memory");
    __syncthreads();
    if (kv0 <= qw + 15) {           // wave-uniform causal skip
      f32x4 sc[4];
#pragma unroll
      for (int f = 0; f < 4; ++f) sc[f] = (f32x4){0.f, 0.f, 0.f, 0.f};
#pragma unroll
      for (int sl = 0; sl < 4; ++sl)
#pragma unroll
        for (int f = 0; f < 4; ++f) {
          // row = f*16+c, row&15 = c -> swizzled chunk = (sl*4+g) ^ c
          bf16x8 kf = *(const bf16x8*)&lK[(f * 16 + c) * 128 + (((sl * 4 + g) ^ c) * 8)];
          sc[f] = __builtin_amdgcn_mfma_f32_16x16x32_bf16(kf, qf[sl], sc[f], 0, 0, 0);
        }
      const float SCL = 0.088388347648318447f * 1.4426950408889634f;  // 1/sqrt(128)*log2(e)
      bool partial = (kv0 + 63 > qw);
      float pvv[4][4];
      float pm = -1e30f;
#pragma unroll
      for (int f = 0; f < 4; ++f)
#pragma unroll
        for (int r = 0; r < 4; ++r) {
          float v = sc[f][r] * SCL;  // S^T: kv = kv0+f*16+4g+r, q = qw+c
          if (partial && (kv0 + f * 16 + 4 * g + r > qw + c)) v = -1e30f;
          pvv[f][r] = v;
          pm = fmaxf(pm, v);
        }
      pm = fmaxf(pm, __shfl_xor(pm, 16));
      pm = fmaxf(pm, __shfl_xor(pm, 32));
      float m_new = fmaxf(m_run, pm);
      float alpha = exp2f(m_run - m_new);
      float ps = 0.f;
#pragma unroll
      for (int f = 0; f < 4; ++f)
#pragma unroll
        for (int r = 0; r < 4; ++r) {
          float p = exp2f(pvv[f][r] - m_new);
          pvv[f][r] = p;
          ps += p;
        }
      ps += __shfl_xor(ps, 16);
      ps += __shfl_xor(ps, 32);
      l_run = l_run * alpha + ps;
      m_run = m_new;
#pragma unroll
      for (int r = 0; r < 4; ++r) {
        float ar = __shfl(alpha, 4 * g + r);
#pragma unroll
        for (int nd = 0; nd < 8; ++nd) oacc[nd][r] *= ar;
      }
      // P -> per-wave LDS tile [q][kv] (bf16, swizzled; register-written so swizzle OK)
      char* Pw = (char*)&lP[w][0];
#pragma unroll
      for (int f = 0; f < 4; ++f) {
        int base = f * 32 + g * 8;
        int chunk = base >> 4, within = base & 15;
        uint32_t p01 = (uint32_t)f2bf(pvv[f][0]) | ((uint32_t)f2bf(pvv[f][1]) << 16);
        uint32_t p23 = (uint32_t)f2bf(pvv[f][2]) | ((uint32_t)f2bf(pvv[f][3]) << 16);
        int rowb = c * 128 + ((chunk ^ (c & 7)) << 4) + within;
        *(uint32_t*)(Pw + rowb)     = p01;
        *(uint32_t*)(Pw + rowb + 4) = p23;
      }
      // PV: O[q][d] += P[q][kv] * V[kv][d]
#pragma unroll
      for (int ks = 0; ks < 2; ++ks) {
        bf16x8 pf = *(const bf16x8*)(Pw + c * 128 + (((ks * 4 + g) ^ (c & 7)) << 4));
#pragma unroll
        for (int nd = 0; nd < 8; ++nd) {
          int rowv = nd * 16 + c;   // rowv&7 = c&7
          bf16x8 vf = *(const bf16x8*)&lV[rowv * 64 + (((ks * 4 + g) ^ (c & 7)) * 8)];
          oacc[nd] = __builtin_amdgcn_mfma_f32_16x16x32_bf16(pf, vf, oacc[nd], 0, 0, 0);
        }
      }
    }
  }
  float lr[4];
#pragma unroll
  for (int r = 0; r < 4; ++r) {
    float lv = __shfl(l_run, 4 * g + r);
    lr[r] = 1.f / lv;
  }
#pragma unroll
  for (int nd = 0; nd < 8; ++nd)
#pragma unroll
    for (int r = 0; r < 4; ++r) {
      size_t row = (size_t)b * S_ + (qw + 4 * g + r);
      O[row * (NH_ * HD_) + h * HD_ + nd * 16 + c] = f2bf(oacc[nd][r] * lr[r]);
    }
}

// ---------------- launch ----------------
extern "C" void kernel_launch(void* const* d_in, const int* in_sizes, int n_in,
                              void* d_out, int out_size, void* d_ws, size_t ws_size,
                              hipStream_t stream) {
  const float* hid   = (const float*)d_in[0];
  // d_in[1] attention_mask: deterministic causal mask -> implemented directly
  const float* rcos  = (const float*)d_in[2];
  const float* rsin  = (const float*)d_in[3];
  const float* wattn = (const float*)d_in[4];
  const float* wproj = (const float*)d_in[5];

  // ws layout (u16 units). Required: ~148 MiB.
  u16* ws   = (u16*)d_ws;
  u16* hidB = ws;                 // 8192*2048
  u16* wAT  = ws + 16777216;      // 3072*2048 (w_attn^T)
  u16* wPT  = ws + 23068672;      // 2048*2048 (w_proj^T)
  u16* qkv  = ws + 27262976;      // 8192*3072
  u16* Qs   = ws + 52428800;      // [B][NH][S][HD]
  u16* Ks   = ws + 69206016;      // [B][NKV][S][HD]
  u16* Vts  = ws + 73400320;      // [B][NKV][HD][S]
  u16* Os   = qkv;                // alias: qkv dead after rope/transpose_v

  k_cvt_bf16<<<16384, 256, 0, stream>>>(hid, hidB, 16777216 / 4);
  k_transpose_cvt<<<dim3(48, 32), 256, 0, stream>>>(wattn, wAT, 2048, 3072);
  k_transpose_cvt<<<dim3(32, 32), 256, 0, stream>>>(wproj, wPT, 2048, 2048);
  k_gemm_bt<false><<<dim3(24, 64), 256, 0, stream>>>(hidB, wAT, qkv, 8192, 3072, 2048);
  k_rope_qk<<<81920, 256, 0, stream>>>(qkv, rcos, rsin, Qs, Ks);
  k_transpose_v<<<dim3(32, 16), 256, 0, stream>>>(qkv, Vts);
  k_flash<<<dim3(16, 64), 512, 0, stream>>>(Qs, Ks, Vts, Os);
  k_gemm_bt<true><<<dim3(16, 64), 256, 0, stream>>>(Os, wPT, d_out, 8192, 2048, 2048);
}

// Round 8
// 605.083 us; speedup vs baseline: 1.2291x; 1.0106x over previous
//
#include <hip/hip_runtime.h>
#include <hip/hip_bf16.h>
#include <stdint.h>

// Problem constants (match reference)
#define B_   4
#define S_   2048
#define H_   2048
#define NH_  16
#define NKV_ 4
#define HD_  128
#define F_   3072   // H + 2*NKV*HD

typedef __bf16 bf16x8 __attribute__((ext_vector_type(8)));
typedef float  f32x4  __attribute__((ext_vector_type(4)));
typedef unsigned short u16;

// global_load_lds: LDS dest is WAVE-UNIFORM base + lane*16 (m104); source is per-lane.
#define GLOAD_LDS16(gp, lp)                                                             \
  __builtin_amdgcn_global_load_lds((const __attribute__((address_space(1))) void*)(gp), \
                                   (__attribute__((address_space(3))) void*)(lp), 16, 0, 0)

__device__ __forceinline__ u16 f2bf(float f) {
  union { float f; uint32_t u; } v; v.f = f;
  uint32_t r = (v.u + 0x7FFFu + ((v.u >> 16) & 1u)) >> 16;  // RNE
  return (u16)r;
}
__device__ __forceinline__ float bf2f(u16 u) {
  union { uint32_t u; float f; } v; v.u = ((uint32_t)u) << 16;
  return v.f;
}

// ---------------- elementwise f32 -> bf16 ----------------
__global__ void k_cvt_bf16(const float* __restrict__ in, u16* __restrict__ out, int n4) {
  int i = blockIdx.x * 256 + threadIdx.x;
  if (i >= n4) return;
  float4 v = ((const float4*)in)[i];
  union { u16 s[4]; uint2 u; } o;
  o.s[0] = f2bf(v.x); o.s[1] = f2bf(v.y); o.s[2] = f2bf(v.z); o.s[3] = f2bf(v.w);
  ((uint2*)out)[i] = o.u;
}

// ---------------- tiled transpose + cvt: out[c][r] = bf16(in[r][c]) ----------------
__global__ void k_transpose_cvt(const float* __restrict__ in, u16* __restrict__ out, int R, int C) {
  __shared__ u16 tile[64][68];
  int c0 = blockIdx.x * 64, r0 = blockIdx.y * 64;
  int t = threadIdx.x;
#pragma unroll
  for (int j = 0; j < 16; ++j) {
    int e = j * 256 + t;
    int r = e >> 6, c = e & 63;
    tile[r][c] = f2bf(in[(size_t)(r0 + r) * C + (c0 + c)]);
  }
  __syncthreads();
#pragma unroll
  for (int j = 0; j < 16; ++j) {
    int e = j * 256 + t;
    int c = e >> 6, r = e & 63;
    out[(size_t)(c0 + c) * R + (r0 + r)] = tile[r][c];
  }
}

// ---------------- bf16 GEMM: C[M][N] = A[M][K] * BT[N][K]^T ----------------
// r5 (kept): T3-minimum double-buffered pipeline + T2 both-sides XOR swizzle.
template <bool OUTF32>
__global__ __launch_bounds__(256) void k_gemm_bt(const u16* __restrict__ A, const u16* __restrict__ BT,
                                                 void* __restrict__ Cv, int M, int N, int K) {
  __shared__ u16 lA[2][128 * 64];
  __shared__ u16 lB[2][128 * 64];
  int t = threadIdx.x, w = t >> 6, l = t & 63, c = l & 15, g = l >> 4;
  int bn = blockIdx.x * 128, bm = blockIdx.y * 128;
  int wm = (w >> 1) * 64, wn = (w & 1) * 64;

  f32x4 acc[4][4];
#pragma unroll
  for (int mi = 0; mi < 4; ++mi)
#pragma unroll
    for (int ni = 0; ni < 4; ++ni) acc[mi][ni] = (f32x4){0.f, 0.f, 0.f, 0.f};

  int nk = K >> 6;
  int srow = l >> 3;                       // row within 1KB chunk (8 rows x 64 u16)
  int scol = ((l & 7) ^ srow) * 8;         // inverse-swizzled source column chunk

#define GEMM_STAGE(k0, buf)                                                     \
  _Pragma("unroll")                                                             \
  for (int i = 0; i < 4; ++i) {                                                 \
    int ch = i * 4 + w; int row = ch * 8 + srow;                                \
    GLOAD_LDS16(&A [(size_t)(bm + row) * K + (k0) + scol], &lA[buf][ch * 512]); \
    GLOAD_LDS16(&BT[(size_t)(bn + row) * K + (k0) + scol], &lB[buf][ch * 512]); \
  }

  GEMM_STAGE(0, 0)
  asm volatile("s_waitcnt vmcnt(0)" ::: "memory");
  __syncthreads();
  int cur = 0;
  for (int kt = 0; kt < nk; ++kt) {
    if (kt + 1 < nk) { GEMM_STAGE((kt + 1) << 6, cur ^ 1) }
    const u16* cA = lA[cur];
    const u16* cB = lB[cur];
#pragma unroll
    for (int s = 0; s < 2; ++s) {
      bf16x8 af[4], bfr[4];
#pragma unroll
      for (int mi = 0; mi < 4; ++mi) {
        int row = wm + mi * 16 + c;        // row&7 = c&7
        af[mi] = *(const bf16x8*)&cA[row * 64 + (((s * 4 + g) ^ (c & 7)) * 8)];
      }
#pragma unroll
      for (int ni = 0; ni < 4; ++ni) {
        int row = wn + ni * 16 + c;
        bfr[ni] = *(const bf16x8*)&cB[row * 64 + (((s * 4 + g) ^ (c & 7)) * 8)];
      }
#pragma unroll
      for (int mi = 0; mi < 4; ++mi)
#pragma unroll
        for (int ni = 0; ni < 4; ++ni)
          acc[mi][ni] = __builtin_amdgcn_mfma_f32_16x16x32_bf16(af[mi], bfr[ni], acc[mi][ni], 0, 0, 0);
    }
    if (kt + 1 < nk) {
      asm volatile("s_waitcnt vmcnt(0)" ::: "memory");
      __syncthreads();
      cur ^= 1;
    }
  }
  // epilogue: D row = 4*g + r, col = c  (m89/m91-verified layout)
#pragma unroll
  for (int mi = 0; mi < 4; ++mi)
#pragma unroll
    for (int ni = 0; ni < 4; ++ni)
#pragma unroll
      for (int r = 0; r < 4; ++r) {
        size_t row = (size_t)bm + wm + mi * 16 + 4 * g + r;
        size_t col = (size_t)bn + wn + ni * 16 + c;
        if constexpr (OUTF32) ((float*)Cv)[row * N + col] = acc[mi][ni][r];
        else                  ((u16*)Cv)  [row * N + col] = f2bf(acc[mi][ni][r]);
      }
#undef GEMM_STAGE
}

// ---------------- RoPE + scatter Q/K from qkv ----------------
__global__ void k_rope_qk(const u16* __restrict__ qkv, const float* __restrict__ ct,
                          const float* __restrict__ st, u16* __restrict__ Q, u16* __restrict__ Kd) {
  size_t idx = (size_t)blockIdx.x * 256 + threadIdx.x;
  const size_t NQ = (size_t)B_ * NH_ * S_ * HD_;  // 2^24
  int d, s, row, col; size_t oidx; u16* dst;
  if (idx < NQ) {
    d = (int)(idx & 127); s = (int)((idx >> 7) & (S_ - 1));
    int h = (int)((idx >> 18) & 15); int b = (int)(idx >> 22);
    row = b * S_ + s;
    col = (h >> 2) * 768 + (h & 3) * 128 + d;
    dst = Q; oidx = idx;
  } else {
    size_t i2 = idx - NQ;
    d = (int)(i2 & 127); s = (int)((i2 >> 7) & (S_ - 1));
    int kvh = (int)((i2 >> 18) & 3); int b = (int)(i2 >> 20);
    row = b * S_ + s;
    col = kvh * 768 + 512 + d;
    dst = Kd; oidx = i2;
  }
  float x  = bf2f(qkv[(size_t)row * F_ + col]);
  float xr = (d < 64) ? -bf2f(qkv[(size_t)row * F_ + col + 64])
                      :  bf2f(qkv[(size_t)row * F_ + col - 64]);
  float o = x * ct[s * HD_ + d] + xr * st[s * HD_ + d];
  dst[oidx] = f2bf(o);
}

// ---------------- V transpose: Vt[b][kvh][d][s] = qkv V part ----------------
__global__ void k_transpose_v(const u16* __restrict__ qkv, u16* __restrict__ Vt) {
  __shared__ u16 tile[64][136];
  int s0 = blockIdx.x * 64;
  int b = blockIdx.y >> 2, kvh = blockIdx.y & 3;
  int t = threadIdx.x;
  const u16* src = qkv + (size_t)(b * S_ + s0) * F_ + kvh * 768 + 640;
#pragma unroll
  for (int j = 0; j < 4; ++j) {
    int e = j * 256 + t;
    int sl = e >> 4, ch = e & 15;
    *(uint4*)&tile[sl][ch * 8] = *(const uint4*)&src[(size_t)sl * F_ + ch * 8];
  }
  __syncthreads();
  u16* dstb = Vt + (size_t)(b * NKV_ + kvh) * HD_ * S_;
#pragma unroll
  for (int j = 0; j < 4; ++j) {
    int e = j * 256 + t;
    int d = e & 127, sc = e >> 7;
    u16 tmp[8];
#pragma unroll
    for (int i = 0; i < 8; ++i) tmp[i] = tile[sc * 8 + i][d];
    *(uint4*)&dstb[(size_t)d * S_ + s0 + sc * 8] = *(const uint4*)tmp;
  }
}

// ---------------- flash attention (causal, GQA) ----------------
// r8: (a) double-buffered K/V — with 8-wave blocks pinned at 2 blocks/CU by (512,4),
// LDS 48->80KB is free (2x80=160KB exact). stage(t+1) issued before compute(t);
// one vmcnt(0)+barrier per tile -> stage drain overlaps compute (r7: serialized).
// (b) T13 defer-max: skip O-rescale + m update when __all(pm - m_run <= 8) (log2
// domain; P <= 2^8, safe in bf16/f32; l and O stay scale-consistent).
__global__ __launch_bounds__(512, 4) void k_flash(const u16* __restrict__ Q, const u16* __restrict__ K,
                                                  const u16* __restrict__ Vt, u16* __restrict__ O) {
  __shared__ u16 lK[2][64 * 128];   // [kv][chunk^(kv&15)] swizzled, 16B chunks
  __shared__ u16 lV[2][128 * 64];   // [d][chunk^(d&7)] swizzled, 16B chunks
  __shared__ u16 lP[8][16 * 64];    // per-wave [q][kv], chunk ^ (q&7) swizzle (reg-written)
  int t = threadIdx.x, w = t >> 6, l = t & 63, c = l & 15, g = l >> 4;
  int qb = (int)(gridDim.x - 1 - blockIdx.x);   // heavy blocks first
  int bh = blockIdx.y;
  int b = bh >> 4, h = bh & 15, kvh = h >> 2;
  int qw = qb * 128 + w * 16;
  const u16* Qb = Q  + (size_t)(b * NH_  + h)   * S_ * HD_;
  const u16* Kb = K  + (size_t)(b * NKV_ + kvh) * S_ * HD_;
  const u16* Vb = Vt + (size_t)(b * NKV_ + kvh) * HD_ * S_;

  bf16x8 qf[4];
#pragma unroll
  for (int sl = 0; sl < 4; ++sl)
    qf[sl] = *(const bf16x8*)&Qb[(size_t)(qw + c) * HD_ + sl * 32 + g * 8];

  f32x4 oacc[8];
#pragma unroll
  for (int nd = 0; nd < 8; ++nd) oacc[nd] = (f32x4){0.f, 0.f, 0.f, 0.f};
  float m_run = -1e30f, l_run = 0.f;

  int ntiles = 2 * qb + 2;
  int krl = l >> 4;                 // local K row in chunk (0..3)
  int vrl = l >> 3;                 // local V row in chunk (0..7)

#define STAGE_KV(kv0, buf)                                                           \
  _Pragma("unroll")                                                                  \
  for (int i = 0; i < 2; ++i) {                                                      \
    int ch = i * 8 + w;                                                              \
    int rrK = ch * 4 + krl;                                                          \
    int jK  = (l & 15) ^ (rrK & 15);                                                 \
    GLOAD_LDS16(&Kb[(size_t)((kv0) + rrK) * HD_ + jK * 8], &lK[buf][ch * 512]);      \
    int rdV = ch * 8 + vrl;                                                          \
    int jV  = (l & 7) ^ (rdV & 7);                                                   \
    GLOAD_LDS16(&Vb[(size_t)rdV * S_ + (kv0) + jV * 8], &lV[buf][ch * 512]);         \
  }

  STAGE_KV(0, 0)
  asm volatile("s_waitcnt vmcnt(0)" ::: "memory");
  __syncthreads();
  int cur = 0;

  for (int kt = 0; kt < ntiles; ++kt) {
    int kv0 = kt * 64;
    if (kt + 1 < ntiles) { STAGE_KV(kv0 + 64, cur ^ 1) }
    const u16* cK = lK[cur];
    const u16* cV = lV[cur];
    if (kv0 <= qw + 15) {           // wave-uniform causal skip
      f32x4 sc[4];
#pragma unroll
      for (int f = 0; f < 4; ++f) sc[f] = (f32x4){0.f, 0.f, 0.f, 0.f};
#pragma unroll
      for (int sl = 0; sl < 4; ++sl)
#pragma unroll
        for (int f = 0; f < 4; ++f) {
          // row = f*16+c, row&15 = c -> swizzled chunk = (sl*4+g) ^ c
          bf16x8 kf = *(const bf16x8*)&cK[(f * 16 + c) * 128 + (((sl * 4 + g) ^ c) * 8)];
          sc[f] = __builtin_amdgcn_mfma_f32_16x16x32_bf16(kf, qf[sl], sc[f], 0, 0, 0);
        }
      const float SCL = 0.088388347648318447f * 1.4426950408889634f;  // 1/sqrt(128)*log2(e)
      bool partial = (kv0 + 63 > qw);
      float pvv[4][4];
      float pm = -1e30f;
#pragma unroll
      for (int f = 0; f < 4; ++f)
#pragma unroll
        for (int r = 0; r < 4; ++r) {
          float v = sc[f][r] * SCL;  // S^T: kv = kv0+f*16+4g+r, q = qw+c
          if (partial && (kv0 + f * 16 + 4 * g + r > qw + c)) v = -1e30f;
          pvv[f][r] = v;
          pm = fmaxf(pm, v);
        }
      pm = fmaxf(pm, __shfl_xor(pm, 16));
      pm = fmaxf(pm, __shfl_xor(pm, 32));   // pm = row max (uniform across g)
      // T13 defer-max: only rescale when the new tile max meaningfully exceeds m_run
      if (!__all(pm - m_run <= 8.0f)) {
        float m_new = fmaxf(m_run, pm);
        float alpha = exp2f(m_run - m_new);
        l_run *= alpha;
#pragma unroll
        for (int r = 0; r < 4; ++r) {
          float ar = __shfl(alpha, 4 * g + r);
#pragma unroll
          for (int nd = 0; nd < 8; ++nd) oacc[nd][r] *= ar;
        }
        m_run = m_new;
      }
      float ps = 0.f;
#pragma unroll
      for (int f = 0; f < 4; ++f)
#pragma unroll
        for (int r = 0; r < 4; ++r) {
          float p = exp2f(pvv[f][r] - m_run);
          pvv[f][r] = p;
          ps += p;
        }
      ps += __shfl_xor(ps, 16);
      ps += __shfl_xor(ps, 32);
      l_run += ps;
      // P -> per-wave LDS tile [q][kv] (bf16, swizzled; register-written so swizzle OK)
      char* Pw = (char*)&lP[w][0];
#pragma unroll
      for (int f = 0; f < 4; ++f) {
        int base = f * 32 + g * 8;
        int chunk = base >> 4, within = base & 15;
        uint32_t p01 = (uint32_t)f2bf(pvv[f][0]) | ((uint32_t)f2bf(pvv[f][1]) << 16);
        uint32_t p23 = (uint32_t)f2bf(pvv[f][2]) | ((uint32_t)f2bf(pvv[f][3]) << 16);
        int rowb = c * 128 + ((chunk ^ (c & 7)) << 4) + within;
        *(uint32_t*)(Pw + rowb)     = p01;
        *(uint32_t*)(Pw + rowb + 4) = p23;
      }
      // PV: O[q][d] += P[q][kv] * V[kv][d]
#pragma unroll
      for (int ks = 0; ks < 2; ++ks) {
        bf16x8 pf = *(const bf16x8*)(Pw + c * 128 + (((ks * 4 + g) ^ (c & 7)) << 4));
#pragma unroll
        for (int nd = 0; nd < 8; ++nd) {
          int rowv = nd * 16 + c;   // rowv&7 = c&7
          bf16x8 vf = *(const bf16x8*)&cV[rowv * 64 + (((ks * 4 + g) ^ (c & 7)) * 8)];
          oacc[nd] = __builtin_amdgcn_mfma_f32_16x16x32_bf16(pf, vf, oacc[nd], 0, 0, 0);
        }
      }
    }
    if (kt + 1 < ntiles) {
      asm volatile("s_waitcnt vmcnt(0)" ::: "memory");
      __syncthreads();
      cur ^= 1;
    }
  }
#undef STAGE_KV
  float lr[4];
#pragma unroll
  for (int r = 0; r < 4; ++r) {
    float lv = __shfl(l_run, 4 * g + r);
    lr[r] = 1.f / lv;
  }
#pragma unroll
  for (int nd = 0; nd < 8; ++nd)
#pragma unroll
    for (int r = 0; r < 4; ++r) {
      size_t row = (size_t)b * S_ + (qw + 4 * g + r);
      O[row * (NH_ * HD_) + h * HD_ + nd * 16 + c] = f2bf(oacc[nd][r] * lr[r]);
    }
}

// ---------------- launch ----------------
extern "C" void kernel_launch(void* const* d_in, const int* in_sizes, int n_in,
                              void* d_out, int out_size, void* d_ws, size_t ws_size,
                              hipStream_t stream) {
  const float* hid   = (const float*)d_in[0];
  // d_in[1] attention_mask: deterministic causal mask -> implemented directly
  const float* rcos  = (const float*)d_in[2];
  const float* rsin  = (const float*)d_in[3];
  const float* wattn = (const float*)d_in[4];
  const float* wproj = (const float*)d_in[5];

  // ws layout (u16 units). Required: ~148 MiB.
  u16* ws   = (u16*)d_ws;
  u16* hidB = ws;                 // 8192*2048
  u16* wAT  = ws + 16777216;      // 3072*2048 (w_attn^T)
  u16* wPT  = ws + 23068672;      // 2048*2048 (w_proj^T)
  u16* qkv  = ws + 27262976;      // 8192*3072
  u16* Qs   = ws + 52428800;      // [B][NH][S][HD]
  u16* Ks   = ws + 69206016;      // [B][NKV][S][HD]
  u16* Vts  = ws + 73400320;      // [B][NKV][HD][S]
  u16* Os   = qkv;                // alias: qkv dead after rope/transpose_v

  k_cvt_bf16<<<16384, 256, 0, stream>>>(hid, hidB, 16777216 / 4);
  k_transpose_cvt<<<dim3(48, 32), 256, 0, stream>>>(wattn, wAT, 2048, 3072);
  k_transpose_cvt<<<dim3(32, 32), 256, 0, stream>>>(wproj, wPT, 2048, 2048);
  k_gemm_bt<false><<<dim3(24, 64), 256, 0, stream>>>(hidB, wAT, qkv, 8192, 3072, 2048);
  k_rope_qk<<<81920, 256, 0, stream>>>(qkv, rcos, rsin, Qs, Ks);
  k_transpose_v<<<dim3(32, 16), 256, 0, stream>>>(qkv, Vts);
  k_flash<<<dim3(16, 64), 512, 0, stream>>>(Qs, Ks, Vts, Os);
  k_gemm_bt<true><<<dim3(16, 64), 256, 0, stream>>>(Os, wPT, d_out, 8192, 2048, 2048);
}